// Round 15
// baseline (300.227 us; speedup 1.0000x reference)
//
#include <hip/hip_runtime.h>

// Dual-key attention, bf16 MFMA pipeline. ws_size >= 42 MiB.
// ws layout (MiB offsets):
//   0: qbf   [b][h][1024][64] bf16   (8 MiB)
//   8: khat  [b][h][1024][64] bf16   (8)
//  16: vT    [b][h][64][1024] bf16   (8)
//  24: attno [b*1024+n][h*64+d] bf16 (8)
//  32: WoT,WqT,Wk1T,Wk2T,WvT bf16 [N][K] (2 MiB each)

typedef short bf16x8 __attribute__((ext_vector_type(8)));
typedef float f32x4 __attribute__((ext_vector_type(4)));

__device__ __forceinline__ unsigned short f2bf(float f) {
  unsigned int u = __float_as_uint(f);
  return (unsigned short)((u + 0x7FFFu + ((u >> 16) & 1u)) >> 16);
}

__device__ __forceinline__ bf16x8 pack8(float4 a, float4 b) {
  bf16x8 r;
  r[0] = (short)f2bf(a.x); r[1] = (short)f2bf(a.y);
  r[2] = (short)f2bf(a.z); r[3] = (short)f2bf(a.w);
  r[4] = (short)f2bf(b.x); r[5] = (short)f2bf(b.y);
  r[6] = (short)f2bf(b.z); r[7] = (short)f2bf(b.w);
  return r;
}

__device__ __forceinline__ void gload_lds16(const void* g, void* l) {
  __builtin_amdgcn_global_load_lds(
      (const __attribute__((address_space(1))) unsigned int*)g,
      (__attribute__((address_space(3))) unsigned int*)l, 16, 0, 0);
}

// ---------------- batched W [1024][1024] fp32 -> W^T bf16 (5 weights) -------
struct W5 { const float *w0, *w1, *w2, *w3, *w4; };

__global__ __launch_bounds__(256) void transpose5_kernel(W5 w, unsigned short* out) {
  __shared__ float tile[32][33];
  const int z = blockIdx.z;
  const float* in = (z == 0) ? w.w0 : (z == 1) ? w.w1 : (z == 2) ? w.w2
                    : (z == 3) ? w.w3 : w.w4;
  unsigned short* o = out + (size_t)z * (1024 * 1024);
  const int x = threadIdx.x & 31;
  const int y0 = (threadIdx.x >> 5) << 2;
  const int r0 = blockIdx.y * 32, c0 = blockIdx.x * 32;
#pragma unroll
  for (int i = 0; i < 4; ++i)
    tile[y0 + i][x] = in[(size_t)(r0 + y0 + i) * 1024 + c0 + x];
  __syncthreads();
#pragma unroll
  for (int i = 0; i < 4; ++i) {
    int c = y0 + i;
    o[(size_t)(c0 + c) * 1024 + r0 + x] = f2bf(tile[x][c]);
  }
}

// ---------------- 64x64-tile, BK=64 MFMA GEMM: C = A1@B1^T (+A2@B2^T) + bias
template <int AMODE>
__global__ __launch_bounds__(256, 4) void gemm64_kernel(
    const void* A1v, const unsigned short* __restrict__ B1,
    const void* A2v, const unsigned short* __restrict__ B2,
    const float* __restrict__ bias1, const float* __restrict__ bias2,
    void* __restrict__ outp, int M, int N, int K, int omode) {
  __shared__ unsigned short lA[2][64 * 64];
  __shared__ unsigned short lB[2][64 * 64];
  const int tid = threadIdx.x;
  const int lane = tid & 63, wave = tid >> 6;
  const int l15 = lane & 15, lg = lane >> 4;
  const int m0 = blockIdx.x * 64, n0 = blockIdx.y * 64;
  const int wr = wave >> 1, wc = wave & 1;
  const int arow = tid >> 2;
  const int acb = (tid & 3) * 32;

  f32x4 zero4 = {0.f, 0.f, 0.f, 0.f};
  f32x4 acc[2][2];
#pragma unroll
  for (int i = 0; i < 2; ++i)
#pragma unroll
    for (int j = 0; j < 2; ++j) acc[i][j] = zero4;

  const int ksteps = K >> 6;
  const int npair = (A2v != nullptr) ? 2 : 1;
  const int nsteps = npair * ksteps;

  {
#pragma unroll
    for (int rep = 0; rep < 2; ++rep) {
      int c = rep * 256 + tid;
      int row = c >> 3;
      int off = ((c & 7) * 16) ^ ((row & 7) << 4);
      gload_lds16(&B1[(size_t)(n0 + row) * K + (off >> 1)],
                  (char*)lB[0] + rep * 4096 + wave * 1024);
      if (AMODE == 1)
        gload_lds16(&((const unsigned short*)A1v)[(size_t)(m0 + row) * K + (off >> 1)],
                    (char*)lA[0] + rep * 4096 + wave * 1024);
    }
    if (AMODE == 0) {
      const float* A = (const float*)A1v;
      const int ce = acb >> 1;
      float4 a0 = *(const float4*)&A[(size_t)(m0 + arow) * K + ce];
      float4 a1 = *(const float4*)&A[(size_t)(m0 + arow) * K + ce + 4];
      float4 a2 = *(const float4*)&A[(size_t)(m0 + arow) * K + ce + 8];
      float4 a3 = *(const float4*)&A[(size_t)(m0 + arow) * K + ce + 12];
      int sw = (arow & 7) << 4;
      *(bf16x8*)((char*)lA[0] + arow * 128 + (acb ^ sw)) = pack8(a0, a1);
      *(bf16x8*)((char*)lA[0] + arow * 128 + ((acb + 16) ^ sw)) = pack8(a2, a3);
    }
  }
  __syncthreads();

  for (int s = 0; s < nsteps; ++s) {
    const int cur = s & 1, nxt = cur ^ 1;
    const bool hn = (s + 1 < nsteps);
    float4 a0, a1, a2, a3;
    if (hn) {
      const int s1 = s + 1;
      const int p1 = (s1 >= ksteps) ? 1 : 0;
      const int k1 = (s1 - p1 * ksteps) * 64;
      const unsigned short* B = p1 ? B2 : B1;
#pragma unroll
      for (int rep = 0; rep < 2; ++rep) {
        int c = rep * 256 + tid;
        int row = c >> 3;
        int off = ((c & 7) * 16) ^ ((row & 7) << 4);
        gload_lds16(&B[(size_t)(n0 + row) * K + k1 + (off >> 1)],
                    (char*)lB[nxt] + rep * 4096 + wave * 1024);
        if (AMODE == 1)
          gload_lds16(&((const unsigned short*)(p1 ? A2v : A1v))
                          [(size_t)(m0 + row) * K + k1 + (off >> 1)],
                      (char*)lA[nxt] + rep * 4096 + wave * 1024);
      }
      if (AMODE == 0) {
        const float* A = (const float*)(p1 ? A2v : A1v);
        const int ce = k1 + (acb >> 1);
        a0 = *(const float4*)&A[(size_t)(m0 + arow) * K + ce];
        a1 = *(const float4*)&A[(size_t)(m0 + arow) * K + ce + 4];
        a2 = *(const float4*)&A[(size_t)(m0 + arow) * K + ce + 8];
        a3 = *(const float4*)&A[(size_t)(m0 + arow) * K + ce + 12];
      }
    }
    bf16x8 af[2][2], bfr[2][2];
#pragma unroll
    for (int mf = 0; mf < 2; ++mf) {
      int row = wr * 32 + mf * 16 + l15;
      int sw = (row & 7) << 4;
#pragma unroll
      for (int kk = 0; kk < 2; ++kk)
        af[mf][kk] = *(const bf16x8*)((const char*)lA[cur] + row * 128 +
                                      ((kk * 64 + lg * 16) ^ sw));
    }
#pragma unroll
    for (int nf = 0; nf < 2; ++nf) {
      int row = wc * 32 + nf * 16 + l15;
      int sw = (row & 7) << 4;
#pragma unroll
      for (int kk = 0; kk < 2; ++kk)
        bfr[nf][kk] = *(const bf16x8*)((const char*)lB[cur] + row * 128 +
                                       ((kk * 64 + lg * 16) ^ sw));
    }
#pragma unroll
    for (int kk = 0; kk < 2; ++kk)
#pragma unroll
      for (int mf = 0; mf < 2; ++mf)
#pragma unroll
        for (int nf = 0; nf < 2; ++nf)
          acc[mf][nf] = __builtin_amdgcn_mfma_f32_16x16x32_bf16(
              af[mf][kk], bfr[nf][kk], acc[mf][nf], 0, 0, 0);
    if (AMODE == 0 && hn) {
      int sw = (arow & 7) << 4;
      *(bf16x8*)((char*)lA[nxt] + arow * 128 + (acb ^ sw)) = pack8(a0, a1);
      *(bf16x8*)((char*)lA[nxt] + arow * 128 + ((acb + 16) ^ sw)) = pack8(a2, a3);
    }
    __syncthreads();
  }

  unsigned short* outb = (unsigned short*)outp;
  float* outf = (float*)outp;
#pragma unroll
  for (int mf = 0; mf < 2; ++mf) {
#pragma unroll
    for (int nf = 0; nf < 2; ++nf) {
      int cg = n0 + wc * 32 + nf * 16 + l15;
      float badd = (bias1 ? bias1[cg] : 0.f) + (bias2 ? bias2[cg] : 0.f);
#pragma unroll
      for (int j = 0; j < 4; ++j) {
        int r = m0 + wr * 32 + mf * 16 + lg * 4 + j;
        float v = acc[mf][nf][j] + badd;
        if (omode == 2) {
          outf[(size_t)r * N + cg] = v;
        } else {
          int bb = r >> 10, nn = r & 1023;
          int hh = cg >> 6, dd = cg & 63;
          if (omode == 0)
            outb[(((size_t)bb * 16 + hh) * 1024 + nn) * 64 + dd] = f2bf(v);
          else
            outb[(((size_t)bb * 16 + hh) * 64 + dd) * 1024 + nn] = f2bf(v);
        }
      }
    }
  }
}

// ---------------- fused dual-key attention (r12 loop, full 16 tiles) -------
// 1024 blocks = (bh, 64-row q-group): exactly 4 resident blocks/CU (the
// register-file cap), zero tail, no kt-split -> no merge kernel, no partial
// traffic. Inner loop is r12's proven structure verbatim: K+V staged dbuf
// via global_load_lds, tile-top aw/mask hoist (QK covers the latency),
// per-wave P tile, one barrier per K-tile. Epilogue normalizes in-kernel.
__global__ __launch_bounds__(256, 4) void attn_kernel(
    const unsigned short* __restrict__ q, const unsigned short* __restrict__ kh,
    const unsigned short* __restrict__ vT, const float* __restrict__ aw,
    const void* __restrict__ msk, unsigned short* __restrict__ attnout) {
  __shared__ unsigned short lK[2][64 * 64];  // [k][d] 128B rows, XOR-swizzled
  __shared__ unsigned short lV[2][64 * 64];  // [d][k] 128B rows, XOR-swizzled
  __shared__ unsigned short lP[4][16 * 64];  // per-wave P tile, swizzled

  const int tid = threadIdx.x, lane = tid & 63, wave = tid >> 6;
  const int l15 = lane & 15, lg = lane >> 4;
  // XCD swizzle (1024 % 8 == 0): each XCD gets 128 consecutive swb = 8 bh ->
  // K/V working set 8 x 256 KB = 2 MB fits the 4 MB per-XCD L2.
  const int bid = blockIdx.x;
  const int swb = (bid & 7) * 128 + (bid >> 3);
  const int bh = swb >> 4;            // [0,64)
  const int qt16 = swb & 15;          // [0,16)
  const int b = bh >> 4, h = bh & 15;
  const int qrow0 = qt16 * 64 + wave * 16;

  // mask dtype detection (wave-uniform): i32 0/1 words are always <=1
  unsigned w0 = ((const unsigned*)msk)[lane];
  const bool mbyte = (__ballot(w0 > 1u) != 0ull);
  const unsigned char* mp8 = (const unsigned char*)msk + (size_t)bh * 1048576;
  const int* mpi = (const int*)msk + (size_t)bh * 1048576;

  const unsigned short* qp = q + (size_t)bh * 65536;
  const unsigned short* kp = kh + (size_t)bh * 65536;
  const unsigned short* vp = vT + (size_t)bh * 65536;
  const float* awp = aw + (size_t)bh * 1048576;

  bf16x8 qf[2];
#pragma unroll
  for (int kk = 0; kk < 2; ++kk)
    qf[kk] = *(const bf16x8*)&qp[(qrow0 + l15) * 64 + kk * 32 + lg * 8];

  f32x4 zero4 = {0.f, 0.f, 0.f, 0.f};
  f32x4 oacc[4];
  float mrun[4], lrun[4];
#pragma unroll
  for (int x = 0; x < 4; ++x) {
    oacc[x] = zero4;
    mrun[x] = -1e30f;
    lrun[x] = 0.f;
  }

  const float scale = 0.08838834764831845f;  // 1/sqrt(128)

  // prologue: stage tile 0 (K and V) into buf 0
#pragma unroll
  for (int rep = 0; rep < 2; ++rep) {
    int c = rep * 256 + tid;
    int row = c >> 3;
    int off = ((c & 7) * 16) ^ ((row & 7) << 4);
    gload_lds16(&kp[(size_t)row * 64 + (off >> 1)],
                (char*)lK[0] + rep * 4096 + wave * 1024);
    gload_lds16(&vp[(size_t)row * 1024 + (off >> 1)],
                (char*)lV[0] + rep * 4096 + wave * 1024);
  }
  __syncthreads();

  for (int kt = 0; kt < 16; ++kt) {
    const int cur = kt & 1, nxt = cur ^ 1;
    if (kt < 15) {
#pragma unroll
      for (int rep = 0; rep < 2; ++rep) {
        int c = rep * 256 + tid;
        int row = c >> 3;
        int off = ((c & 7) * 16) ^ ((row & 7) << 4);
        gload_lds16(&kp[(size_t)((kt + 1) * 64 + row) * 64 + (off >> 1)],
                    (char*)lK[nxt] + rep * 4096 + wave * 1024);
        gload_lds16(&vp[(size_t)row * 1024 + (kt + 1) * 64 + (off >> 1)],
                    (char*)lV[nxt] + rep * 4096 + wave * 1024);
      }
    }

    // aw/mask for the whole tile hoisted here: QK below covers their latency
    float awc[4][4];
    unsigned mkc[4];
#pragma unroll
    for (int j = 0; j < 4; ++j) {
      const int r = qrow0 + lg * 4 + j;
      const float* awrow = awp + (size_t)r * 1024 + kt * 64;
      const size_t mb = (size_t)r * 1024 + kt * 64;
      unsigned mk = 0;
      if (mbyte) {
#pragma unroll
        for (int nf = 0; nf < 4; ++nf) {
          awc[j][nf] = awrow[nf * 16 + l15];
          mk |= ((unsigned)mp8[mb + nf * 16 + l15] & 1u) << nf;
        }
      } else {
#pragma unroll
        for (int nf = 0; nf < 4; ++nf) {
          awc[j][nf] = awrow[nf * 16 + l15];
          mk |= ((unsigned)(mpi[mb + nf * 16 + l15] != 0)) << nf;
        }
      }
      mkc[j] = mk;
    }

    // S = Q @ K^T : 16 q-rows x 64 k-cols (K from LDS)
    f32x4 sacc[4];
#pragma unroll
    for (int nf = 0; nf < 4; ++nf) sacc[nf] = zero4;
#pragma unroll
    for (int kk = 0; kk < 2; ++kk) {
      bf16x8 kf[4];
#pragma unroll
      for (int nf = 0; nf < 4; ++nf) {
        int row = nf * 16 + l15;
        int off = (kk * 64 + lg * 16) ^ ((row & 7) << 4);
        kf[nf] = *(const bf16x8*)((const char*)lK[cur] + row * 128 + off);
      }
#pragma unroll
      for (int nf = 0; nf < 4; ++nf)
        sacc[nf] = __builtin_amdgcn_mfma_f32_16x16x32_bf16(qf[kk], kf[nf],
                                                           sacc[nf], 0, 0, 0);
    }

    // scale*aw (prefetched), mask, online softmax; P -> per-wave LDS tile
    float alpha[4];
#pragma unroll
    for (int j = 0; j < 4; ++j) {
      float mx = -1e30f;
#pragma unroll
      for (int nf = 0; nf < 4; ++nf) {
        float s = sacc[nf][j] * scale * awc[j][nf];
        s = ((mkc[j] >> nf) & 1u) ? -1e30f : s;
        sacc[nf][j] = s;
        mx = fmaxf(mx, s);
      }
      mx = fmaxf(mx, __shfl_xor(mx, 1));
      mx = fmaxf(mx, __shfl_xor(mx, 2));
      mx = fmaxf(mx, __shfl_xor(mx, 4));
      mx = fmaxf(mx, __shfl_xor(mx, 8));
      float mnew = fmaxf(mrun[j], mx);
      float al = __expf(mrun[j] - mnew);
      mrun[j] = mnew;
      float psum = 0.f;
      const int prow = lg * 4 + j;
      const int swp = (prow & 7) << 4;
#pragma unroll
      for (int nf = 0; nf < 4; ++nf) {
        float s = sacc[nf][j];
        float p = (s <= -1e29f) ? 0.f : __expf(s - mnew);
        psum += p;
        *(unsigned short*)((char*)lP[wave] + prow * 128 +
                           (((nf * 16 + l15) * 2) ^ swp)) = f2bf(p);
      }
      psum += __shfl_xor(psum, 1);
      psum += __shfl_xor(psum, 2);
      psum += __shfl_xor(psum, 4);
      psum += __shfl_xor(psum, 8);
      lrun[j] = lrun[j] * al + psum;
      alpha[j] = al;
    }
#pragma unroll
    for (int df = 0; df < 4; ++df)
#pragma unroll
      for (int j = 0; j < 4; ++j) oacc[df][j] *= alpha[j];

    // O += P @ V  (both from LDS)
#pragma unroll
    for (int kk2 = 0; kk2 < 2; ++kk2) {
      bf16x8 pf;
      {
        int off = (kk2 * 64 + lg * 16) ^ ((l15 & 7) << 4);
        pf = *(const bf16x8*)((const char*)lP[wave] + l15 * 128 + off);
      }
#pragma unroll
      for (int df = 0; df < 4; ++df) {
        int row = df * 16 + l15;
        int off = (kk2 * 64 + lg * 16) ^ ((row & 7) << 4);
        bf16x8 vf = *(const bf16x8*)((const char*)lV[cur] + row * 128 + off);
        oacc[df] = __builtin_amdgcn_mfma_f32_16x16x32_bf16(pf, vf,
                                                           oacc[df], 0, 0, 0);
      }
    }
    __syncthreads();  // next K/V tiles staged; all lK/lV[cur]/lP reads done
  }

  // epilogue: normalize and store attnout bf16 [b*1024+r][h*64+d]
#pragma unroll
  for (int j = 0; j < 4; ++j) {
    int r = qrow0 + lg * 4 + j;
    float inv = 1.0f / lrun[j];
#pragma unroll
    for (int df = 0; df < 4; ++df)
      attnout[((size_t)(b * 1024 + r)) * 1024 + h * 64 + df * 16 + l15] =
          f2bf(oacc[df][j] * inv);
  }
}

extern "C" void kernel_launch(void* const* d_in, const int* in_sizes, int n_in,
                              void* d_out, int out_size, void* d_ws, size_t ws_size,
                              hipStream_t stream) {
  const float* queries = (const float*)d_in[0];
  const float* keys1 = (const float*)d_in[1];
  const float* keys2 = (const float*)d_in[2];
  const float* values = (const float*)d_in[3];
  const float* aw = (const float*)d_in[4];
  const void* mask = d_in[5];
  const float* Wq = (const float*)d_in[6];
  const float* bq = (const float*)d_in[7];
  const float* Wk1 = (const float*)d_in[8];
  const float* bk1 = (const float*)d_in[9];
  const float* Wk2 = (const float*)d_in[10];
  const float* bk2 = (const float*)d_in[11];
  const float* Wv = (const float*)d_in[12];
  const float* bv = (const float*)d_in[13];
  const float* Wo = (const float*)d_in[14];
  const float* bo = (const float*)d_in[15];

  char* ws = (char*)d_ws;
  unsigned short* qbf = (unsigned short*)(ws + (0ull << 20));
  unsigned short* khat = (unsigned short*)(ws + (8ull << 20));
  unsigned short* vTb = (unsigned short*)(ws + (16ull << 20));
  unsigned short* attno = (unsigned short*)(ws + (24ull << 20));
  unsigned short* WT = (unsigned short*)(ws + (32ull << 20));
  unsigned short* WoT = WT;
  unsigned short* WqT = WT + 1 * 1048576;
  unsigned short* Wk1T = WT + 2 * 1048576;
  unsigned short* Wk2T = WT + 3 * 1048576;
  unsigned short* WvT = WT + 4 * 1048576;

  transpose5_kernel<<<dim3(32, 32, 5), 256, 0, stream>>>(
      W5{Wo, Wq, Wk1, Wk2, Wv}, WT);

  const dim3 gg(64, 16);  // M/64, N/64
  gemm64_kernel<0><<<gg, 256, 0, stream>>>(queries, WqT, nullptr, nullptr,
                                           bq, nullptr, qbf, 4096, 1024, 1024, 0);
  gemm64_kernel<0><<<gg, 256, 0, stream>>>(keys1, Wk1T, keys2, Wk2T,
                                           bk1, bk2, khat, 4096, 1024, 1024, 0);
  gemm64_kernel<0><<<gg, 256, 0, stream>>>(values, WvT, nullptr, nullptr,
                                           bv, nullptr, vTb, 4096, 1024, 1024, 1);

  attn_kernel<<<1024, 256, 0, stream>>>(qbf, khat, vTb, aw, mask, attno);

  gemm64_kernel<1><<<gg, 256, 0, stream>>>(attno, WoT, nullptr, nullptr,
                                           bo, nullptr, d_out, 4096, 1024, 1024, 2);
}

// Round 16
// 269.298 us; speedup vs baseline: 1.1148x; 1.1148x over previous
//
#include <hip/hip_runtime.h>

// Dual-key attention, bf16 MFMA pipeline. ws_size >= 42 MiB.
// ws layout (MiB offsets):
//   0: qbf   [b][h][1024][64] bf16   (8 MiB)
//   8: khat  [b][h][1024][64] bf16   (8)
//  16: vT    [b][h][64][1024] bf16   (8)
//  24: attno [b*1024+n][h*64+d] bf16 (8)
//  32: WoT,WqT,Wk1T,Wk2T,WvT bf16 [N][K] (2 MiB each)

typedef short bf16x8 __attribute__((ext_vector_type(8)));
typedef float f32x4 __attribute__((ext_vector_type(4)));

__device__ __forceinline__ unsigned short f2bf(float f) {
  unsigned int u = __float_as_uint(f);
  return (unsigned short)((u + 0x7FFFu + ((u >> 16) & 1u)) >> 16);
}

__device__ __forceinline__ bf16x8 pack8(float4 a, float4 b) {
  bf16x8 r;
  r[0] = (short)f2bf(a.x); r[1] = (short)f2bf(a.y);
  r[2] = (short)f2bf(a.z); r[3] = (short)f2bf(a.w);
  r[4] = (short)f2bf(b.x); r[5] = (short)f2bf(b.y);
  r[6] = (short)f2bf(b.z); r[7] = (short)f2bf(b.w);
  return r;
}

__device__ __forceinline__ void gload_lds16(const void* g, void* l) {
  __builtin_amdgcn_global_load_lds(
      (const __attribute__((address_space(1))) unsigned int*)g,
      (__attribute__((address_space(3))) unsigned int*)l, 16, 0, 0);
}

// ---------------- batched W [1024][1024] fp32 -> W^T bf16 (5 weights) -------
struct W5 { const float *w0, *w1, *w2, *w3, *w4; };

__global__ __launch_bounds__(256) void transpose5_kernel(W5 w, unsigned short* out) {
  __shared__ float tile[32][33];
  const int z = blockIdx.z;
  const float* in = (z == 0) ? w.w0 : (z == 1) ? w.w1 : (z == 2) ? w.w2
                    : (z == 3) ? w.w3 : w.w4;
  unsigned short* o = out + (size_t)z * (1024 * 1024);
  const int x = threadIdx.x & 31;
  const int y0 = (threadIdx.x >> 5) << 2;
  const int r0 = blockIdx.y * 32, c0 = blockIdx.x * 32;
#pragma unroll
  for (int i = 0; i < 4; ++i)
    tile[y0 + i][x] = in[(size_t)(r0 + y0 + i) * 1024 + c0 + x];
  __syncthreads();
#pragma unroll
  for (int i = 0; i < 4; ++i) {
    int c = y0 + i;
    o[(size_t)(c0 + c) * 1024 + r0 + x] = f2bf(tile[x][c]);
  }
}

// ---------------- fused 3-projection GEMM (q / khat / v) --------------------
// One 3072-block launch: op = bid>>10 (0:q, 1:khat dual-A, 2:v-transposed).
// Same 64x64/BK=64 dbuf structure as gemm64; removes 2 device-wide launch
// drains + tail ramps between the projection GEMMs.
struct P3 {
  const float *qa, *k1a, *k2a, *va;          // fp32 A matrices
  const unsigned short *wq, *wk1, *wk2, *wv; // bf16 W^T
  const float *bq, *bk1, *bk2, *bv;          // biases
  unsigned short *oq, *okh, *ov;             // outputs
};

__global__ __launch_bounds__(256, 4) void proj3_kernel(P3 p) {
  __shared__ unsigned short lA[2][64 * 64];
  __shared__ unsigned short lB[2][64 * 64];
  const int tid = threadIdx.x;
  const int lane = tid & 63, wave = tid >> 6;
  const int l15 = lane & 15, lg = lane >> 4;
  const int bid = blockIdx.x;
  const int op = bid >> 10;                 // 0,1,2
  const int lb = bid & 1023;
  const int m0 = (lb >> 4) * 64, n0 = (lb & 15) * 64;
  const int wr = wave >> 1, wc = wave & 1;
  const int arow = tid >> 2;
  const int acb = (tid & 3) * 32;
  const int K = 1024;

  const float* A1 = (op == 0) ? p.qa : (op == 1) ? p.k1a : p.va;
  const float* A2 = (op == 1) ? p.k2a : nullptr;
  const unsigned short* B1 = (op == 0) ? p.wq : (op == 1) ? p.wk1 : p.wv;
  const unsigned short* B2 = (op == 1) ? p.wk2 : nullptr;
  const float* bias1 = (op == 0) ? p.bq : (op == 1) ? p.bk1 : p.bv;
  const float* bias2 = (op == 1) ? p.bk2 : nullptr;
  unsigned short* outb = (op == 0) ? p.oq : (op == 1) ? p.okh : p.ov;
  const int omode = (op == 2) ? 1 : 0;

  f32x4 zero4 = {0.f, 0.f, 0.f, 0.f};
  f32x4 acc[2][2];
#pragma unroll
  for (int i = 0; i < 2; ++i)
#pragma unroll
    for (int j = 0; j < 2; ++j) acc[i][j] = zero4;

  const int ksteps = K >> 6;
  const int npair = (op == 1) ? 2 : 1;
  const int nsteps = npair * ksteps;

  {
#pragma unroll
    for (int rep = 0; rep < 2; ++rep) {
      int c = rep * 256 + tid;
      int row = c >> 3;
      int off = ((c & 7) * 16) ^ ((row & 7) << 4);
      gload_lds16(&B1[(size_t)(n0 + row) * K + (off >> 1)],
                  (char*)lB[0] + rep * 4096 + wave * 1024);
    }
    const int ce = acb >> 1;
    float4 a0 = *(const float4*)&A1[(size_t)(m0 + arow) * K + ce];
    float4 a1 = *(const float4*)&A1[(size_t)(m0 + arow) * K + ce + 4];
    float4 a2 = *(const float4*)&A1[(size_t)(m0 + arow) * K + ce + 8];
    float4 a3 = *(const float4*)&A1[(size_t)(m0 + arow) * K + ce + 12];
    int sw = (arow & 7) << 4;
    *(bf16x8*)((char*)lA[0] + arow * 128 + (acb ^ sw)) = pack8(a0, a1);
    *(bf16x8*)((char*)lA[0] + arow * 128 + ((acb + 16) ^ sw)) = pack8(a2, a3);
  }
  __syncthreads();

  for (int s = 0; s < nsteps; ++s) {
    const int cur = s & 1, nxt = cur ^ 1;
    const bool hn = (s + 1 < nsteps);
    float4 a0, a1, a2, a3;
    if (hn) {
      const int s1 = s + 1;
      const int p1 = (s1 >= ksteps) ? 1 : 0;
      const int k1 = (s1 - p1 * ksteps) * 64;
      const unsigned short* B = p1 ? B2 : B1;
#pragma unroll
      for (int rep = 0; rep < 2; ++rep) {
        int c = rep * 256 + tid;
        int row = c >> 3;
        int off = ((c & 7) * 16) ^ ((row & 7) << 4);
        gload_lds16(&B[(size_t)(n0 + row) * K + k1 + (off >> 1)],
                    (char*)lB[nxt] + rep * 4096 + wave * 1024);
      }
      const float* A = p1 ? A2 : A1;
      const int ce = k1 + (acb >> 1);
      a0 = *(const float4*)&A[(size_t)(m0 + arow) * K + ce];
      a1 = *(const float4*)&A[(size_t)(m0 + arow) * K + ce + 4];
      a2 = *(const float4*)&A[(size_t)(m0 + arow) * K + ce + 8];
      a3 = *(const float4*)&A[(size_t)(m0 + arow) * K + ce + 12];
    }
    bf16x8 af[2][2], bfr[2][2];
#pragma unroll
    for (int mf = 0; mf < 2; ++mf) {
      int row = wr * 32 + mf * 16 + l15;
      int sw = (row & 7) << 4;
#pragma unroll
      for (int kk = 0; kk < 2; ++kk)
        af[mf][kk] = *(const bf16x8*)((const char*)lA[cur] + row * 128 +
                                      ((kk * 64 + lg * 16) ^ sw));
    }
#pragma unroll
    for (int nf = 0; nf < 2; ++nf) {
      int row = wc * 32 + nf * 16 + l15;
      int sw = (row & 7) << 4;
#pragma unroll
      for (int kk = 0; kk < 2; ++kk)
        bfr[nf][kk] = *(const bf16x8*)((const char*)lB[cur] + row * 128 +
                                       ((kk * 64 + lg * 16) ^ sw));
    }
#pragma unroll
    for (int kk = 0; kk < 2; ++kk)
#pragma unroll
      for (int mf = 0; mf < 2; ++mf)
#pragma unroll
        for (int nf = 0; nf < 2; ++nf)
          acc[mf][nf] = __builtin_amdgcn_mfma_f32_16x16x32_bf16(
              af[mf][kk], bfr[nf][kk], acc[mf][nf], 0, 0, 0);
    if (hn) {
      int sw = (arow & 7) << 4;
      *(bf16x8*)((char*)lA[nxt] + arow * 128 + (acb ^ sw)) = pack8(a0, a1);
      *(bf16x8*)((char*)lA[nxt] + arow * 128 + ((acb + 16) ^ sw)) = pack8(a2, a3);
    }
    __syncthreads();
  }

#pragma unroll
  for (int mf = 0; mf < 2; ++mf) {
#pragma unroll
    for (int nf = 0; nf < 2; ++nf) {
      int cg = n0 + wc * 32 + nf * 16 + l15;
      float badd = bias1[cg] + (bias2 ? bias2[cg] : 0.f);
#pragma unroll
      for (int j = 0; j < 4; ++j) {
        int r = m0 + wr * 32 + mf * 16 + lg * 4 + j;
        float v = acc[mf][nf][j] + badd;
        int bb = r >> 10, nn = r & 1023;
        int hh = cg >> 6, dd = cg & 63;
        if (omode == 0)
          outb[(((size_t)bb * 16 + hh) * 1024 + nn) * 64 + dd] = f2bf(v);
        else
          outb[(((size_t)bb * 16 + hh) * 64 + dd) * 1024 + nn] = f2bf(v);
      }
    }
  }
}

// ---------------- 64x64-tile, BK=64 MFMA GEMM (out-projection) -------------
template <int AMODE>
__global__ __launch_bounds__(256, 4) void gemm64_kernel(
    const void* A1v, const unsigned short* __restrict__ B1,
    const void* A2v, const unsigned short* __restrict__ B2,
    const float* __restrict__ bias1, const float* __restrict__ bias2,
    void* __restrict__ outp, int M, int N, int K, int omode) {
  __shared__ unsigned short lA[2][64 * 64];
  __shared__ unsigned short lB[2][64 * 64];
  const int tid = threadIdx.x;
  const int lane = tid & 63, wave = tid >> 6;
  const int l15 = lane & 15, lg = lane >> 4;
  const int m0 = blockIdx.x * 64, n0 = blockIdx.y * 64;
  const int wr = wave >> 1, wc = wave & 1;
  const int arow = tid >> 2;
  const int acb = (tid & 3) * 32;

  f32x4 zero4 = {0.f, 0.f, 0.f, 0.f};
  f32x4 acc[2][2];
#pragma unroll
  for (int i = 0; i < 2; ++i)
#pragma unroll
    for (int j = 0; j < 2; ++j) acc[i][j] = zero4;

  const int ksteps = K >> 6;
  const int npair = (A2v != nullptr) ? 2 : 1;
  const int nsteps = npair * ksteps;

  {
#pragma unroll
    for (int rep = 0; rep < 2; ++rep) {
      int c = rep * 256 + tid;
      int row = c >> 3;
      int off = ((c & 7) * 16) ^ ((row & 7) << 4);
      gload_lds16(&B1[(size_t)(n0 + row) * K + (off >> 1)],
                  (char*)lB[0] + rep * 4096 + wave * 1024);
      if (AMODE == 1)
        gload_lds16(&((const unsigned short*)A1v)[(size_t)(m0 + row) * K + (off >> 1)],
                    (char*)lA[0] + rep * 4096 + wave * 1024);
    }
    if (AMODE == 0) {
      const float* A = (const float*)A1v;
      const int ce = acb >> 1;
      float4 a0 = *(const float4*)&A[(size_t)(m0 + arow) * K + ce];
      float4 a1 = *(const float4*)&A[(size_t)(m0 + arow) * K + ce + 4];
      float4 a2 = *(const float4*)&A[(size_t)(m0 + arow) * K + ce + 8];
      float4 a3 = *(const float4*)&A[(size_t)(m0 + arow) * K + ce + 12];
      int sw = (arow & 7) << 4;
      *(bf16x8*)((char*)lA[0] + arow * 128 + (acb ^ sw)) = pack8(a0, a1);
      *(bf16x8*)((char*)lA[0] + arow * 128 + ((acb + 16) ^ sw)) = pack8(a2, a3);
    }
  }
  __syncthreads();

  for (int s = 0; s < nsteps; ++s) {
    const int cur = s & 1, nxt = cur ^ 1;
    const bool hn = (s + 1 < nsteps);
    float4 a0, a1, a2, a3;
    if (hn) {
      const int s1 = s + 1;
      const int p1 = (s1 >= ksteps) ? 1 : 0;
      const int k1 = (s1 - p1 * ksteps) * 64;
      const unsigned short* B = p1 ? B2 : B1;
#pragma unroll
      for (int rep = 0; rep < 2; ++rep) {
        int c = rep * 256 + tid;
        int row = c >> 3;
        int off = ((c & 7) * 16) ^ ((row & 7) << 4);
        gload_lds16(&B[(size_t)(n0 + row) * K + k1 + (off >> 1)],
                    (char*)lB[nxt] + rep * 4096 + wave * 1024);
        if (AMODE == 1)
          gload_lds16(&((const unsigned short*)(p1 ? A2v : A1v))
                          [(size_t)(m0 + row) * K + k1 + (off >> 1)],
                      (char*)lA[nxt] + rep * 4096 + wave * 1024);
      }
      if (AMODE == 0) {
        const float* A = (const float*)(p1 ? A2v : A1v);
        const int ce = k1 + (acb >> 1);
        a0 = *(const float4*)&A[(size_t)(m0 + arow) * K + ce];
        a1 = *(const float4*)&A[(size_t)(m0 + arow) * K + ce + 4];
        a2 = *(const float4*)&A[(size_t)(m0 + arow) * K + ce + 8];
        a3 = *(const float4*)&A[(size_t)(m0 + arow) * K + ce + 12];
      }
    }
    bf16x8 af[2][2], bfr[2][2];
#pragma unroll
    for (int mf = 0; mf < 2; ++mf) {
      int row = wr * 32 + mf * 16 + l15;
      int sw = (row & 7) << 4;
#pragma unroll
      for (int kk = 0; kk < 2; ++kk)
        af[mf][kk] = *(const bf16x8*)((const char*)lA[cur] + row * 128 +
                                      ((kk * 64 + lg * 16) ^ sw));
    }
#pragma unroll
    for (int nf = 0; nf < 2; ++nf) {
      int row = wc * 32 + nf * 16 + l15;
      int sw = (row & 7) << 4;
#pragma unroll
      for (int kk = 0; kk < 2; ++kk)
        bfr[nf][kk] = *(const bf16x8*)((const char*)lB[cur] + row * 128 +
                                       ((kk * 64 + lg * 16) ^ sw));
    }
#pragma unroll
    for (int kk = 0; kk < 2; ++kk)
#pragma unroll
      for (int mf = 0; mf < 2; ++mf)
#pragma unroll
        for (int nf = 0; nf < 2; ++nf)
          acc[mf][nf] = __builtin_amdgcn_mfma_f32_16x16x32_bf16(
              af[mf][kk], bfr[nf][kk], acc[mf][nf], 0, 0, 0);
    if (AMODE == 0 && hn) {
      int sw = (arow & 7) << 4;
      *(bf16x8*)((char*)lA[nxt] + arow * 128 + (acb ^ sw)) = pack8(a0, a1);
      *(bf16x8*)((char*)lA[nxt] + arow * 128 + ((acb + 16) ^ sw)) = pack8(a2, a3);
    }
    __syncthreads();
  }

  unsigned short* outb = (unsigned short*)outp;
  float* outf = (float*)outp;
#pragma unroll
  for (int mf = 0; mf < 2; ++mf) {
#pragma unroll
    for (int nf = 0; nf < 2; ++nf) {
      int cg = n0 + wc * 32 + nf * 16 + l15;
      float badd = (bias1 ? bias1[cg] : 0.f) + (bias2 ? bias2[cg] : 0.f);
#pragma unroll
      for (int j = 0; j < 4; ++j) {
        int r = m0 + wr * 32 + mf * 16 + lg * 4 + j;
        float v = acc[mf][nf][j] + badd;
        if (omode == 2) {
          outf[(size_t)r * N + cg] = v;
        } else {
          int bb = r >> 10, nn = r & 1023;
          int hh = cg >> 6, dd = cg & 63;
          if (omode == 0)
            outb[(((size_t)bb * 16 + hh) * 1024 + nn) * 64 + dd] = f2bf(v);
          else
            outb[(((size_t)bb * 16 + hh) * 64 + dd) * 1024 + nn] = f2bf(v);
        }
      }
    }
  }
}

// ---------------- fused dual-key attention (r15, unchanged) ----------------
__global__ __launch_bounds__(256, 4) void attn_kernel(
    const unsigned short* __restrict__ q, const unsigned short* __restrict__ kh,
    const unsigned short* __restrict__ vT, const float* __restrict__ aw,
    const void* __restrict__ msk, unsigned short* __restrict__ attnout) {
  __shared__ unsigned short lK[2][64 * 64];  // [k][d] 128B rows, XOR-swizzled
  __shared__ unsigned short lV[2][64 * 64];  // [d][k] 128B rows, XOR-swizzled
  __shared__ unsigned short lP[4][16 * 64];  // per-wave P tile, swizzled

  const int tid = threadIdx.x, lane = tid & 63, wave = tid >> 6;
  const int l15 = lane & 15, lg = lane >> 4;
  const int bid = blockIdx.x;
  const int swb = (bid & 7) * 128 + (bid >> 3);
  const int bh = swb >> 4;            // [0,64)
  const int qt16 = swb & 15;          // [0,16)
  const int b = bh >> 4, h = bh & 15;
  const int qrow0 = qt16 * 64 + wave * 16;

  unsigned w0 = ((const unsigned*)msk)[lane];
  const bool mbyte = (__ballot(w0 > 1u) != 0ull);
  const unsigned char* mp8 = (const unsigned char*)msk + (size_t)bh * 1048576;
  const int* mpi = (const int*)msk + (size_t)bh * 1048576;

  const unsigned short* qp = q + (size_t)bh * 65536;
  const unsigned short* kp = kh + (size_t)bh * 65536;
  const unsigned short* vp = vT + (size_t)bh * 65536;
  const float* awp = aw + (size_t)bh * 1048576;

  bf16x8 qf[2];
#pragma unroll
  for (int kk = 0; kk < 2; ++kk)
    qf[kk] = *(const bf16x8*)&qp[(qrow0 + l15) * 64 + kk * 32 + lg * 8];

  f32x4 zero4 = {0.f, 0.f, 0.f, 0.f};
  f32x4 oacc[4];
  float mrun[4], lrun[4];
#pragma unroll
  for (int x = 0; x < 4; ++x) {
    oacc[x] = zero4;
    mrun[x] = -1e30f;
    lrun[x] = 0.f;
  }

  const float scale = 0.08838834764831845f;  // 1/sqrt(128)

#pragma unroll
  for (int rep = 0; rep < 2; ++rep) {
    int c = rep * 256 + tid;
    int row = c >> 3;
    int off = ((c & 7) * 16) ^ ((row & 7) << 4);
    gload_lds16(&kp[(size_t)row * 64 + (off >> 1)],
                (char*)lK[0] + rep * 4096 + wave * 1024);
    gload_lds16(&vp[(size_t)row * 1024 + (off >> 1)],
                (char*)lV[0] + rep * 4096 + wave * 1024);
  }
  __syncthreads();

  for (int kt = 0; kt < 16; ++kt) {
    const int cur = kt & 1, nxt = cur ^ 1;
    if (kt < 15) {
#pragma unroll
      for (int rep = 0; rep < 2; ++rep) {
        int c = rep * 256 + tid;
        int row = c >> 3;
        int off = ((c & 7) * 16) ^ ((row & 7) << 4);
        gload_lds16(&kp[(size_t)((kt + 1) * 64 + row) * 64 + (off >> 1)],
                    (char*)lK[nxt] + rep * 4096 + wave * 1024);
        gload_lds16(&vp[(size_t)row * 1024 + (kt + 1) * 64 + (off >> 1)],
                    (char*)lV[nxt] + rep * 4096 + wave * 1024);
      }
    }

    float awc[4][4];
    unsigned mkc[4];
#pragma unroll
    for (int j = 0; j < 4; ++j) {
      const int r = qrow0 + lg * 4 + j;
      const float* awrow = awp + (size_t)r * 1024 + kt * 64;
      const size_t mb = (size_t)r * 1024 + kt * 64;
      unsigned mk = 0;
      if (mbyte) {
#pragma unroll
        for (int nf = 0; nf < 4; ++nf) {
          awc[j][nf] = awrow[nf * 16 + l15];
          mk |= ((unsigned)mp8[mb + nf * 16 + l15] & 1u) << nf;
        }
      } else {
#pragma unroll
        for (int nf = 0; nf < 4; ++nf) {
          awc[j][nf] = awrow[nf * 16 + l15];
          mk |= ((unsigned)(mpi[mb + nf * 16 + l15] != 0)) << nf;
        }
      }
      mkc[j] = mk;
    }

    f32x4 sacc[4];
#pragma unroll
    for (int nf = 0; nf < 4; ++nf) sacc[nf] = zero4;
#pragma unroll
    for (int kk = 0; kk < 2; ++kk) {
      bf16x8 kf[4];
#pragma unroll
      for (int nf = 0; nf < 4; ++nf) {
        int row = nf * 16 + l15;
        int off = (kk * 64 + lg * 16) ^ ((row & 7) << 4);
        kf[nf] = *(const bf16x8*)((const char*)lK[cur] + row * 128 + off);
      }
#pragma unroll
      for (int nf = 0; nf < 4; ++nf)
        sacc[nf] = __builtin_amdgcn_mfma_f32_16x16x32_bf16(qf[kk], kf[nf],
                                                           sacc[nf], 0, 0, 0);
    }

    float alpha[4];
#pragma unroll
    for (int j = 0; j < 4; ++j) {
      float mx = -1e30f;
#pragma unroll
      for (int nf = 0; nf < 4; ++nf) {
        float s = sacc[nf][j] * scale * awc[j][nf];
        s = ((mkc[j] >> nf) & 1u) ? -1e30f : s;
        sacc[nf][j] = s;
        mx = fmaxf(mx, s);
      }
      mx = fmaxf(mx, __shfl_xor(mx, 1));
      mx = fmaxf(mx, __shfl_xor(mx, 2));
      mx = fmaxf(mx, __shfl_xor(mx, 4));
      mx = fmaxf(mx, __shfl_xor(mx, 8));
      float mnew = fmaxf(mrun[j], mx);
      float al = __expf(mrun[j] - mnew);
      mrun[j] = mnew;
      float psum = 0.f;
      const int prow = lg * 4 + j;
      const int swp = (prow & 7) << 4;
#pragma unroll
      for (int nf = 0; nf < 4; ++nf) {
        float s = sacc[nf][j];
        float p = (s <= -1e29f) ? 0.f : __expf(s - mnew);
        psum += p;
        *(unsigned short*)((char*)lP[wave] + prow * 128 +
                           (((nf * 16 + l15) * 2) ^ swp)) = f2bf(p);
      }
      psum += __shfl_xor(psum, 1);
      psum += __shfl_xor(psum, 2);
      psum += __shfl_xor(psum, 4);
      psum += __shfl_xor(psum, 8);
      lrun[j] = lrun[j] * al + psum;
      alpha[j] = al;
    }
#pragma unroll
    for (int df = 0; df < 4; ++df)
#pragma unroll
      for (int j = 0; j < 4; ++j) oacc[df][j] *= alpha[j];

#pragma unroll
    for (int kk2 = 0; kk2 < 2; ++kk2) {
      bf16x8 pf;
      {
        int off = (kk2 * 64 + lg * 16) ^ ((l15 & 7) << 4);
        pf = *(const bf16x8*)((const char*)lP[wave] + l15 * 128 + off);
      }
#pragma unroll
      for (int df = 0; df < 4; ++df) {
        int row = df * 16 + l15;
        int off = (kk2 * 64 + lg * 16) ^ ((row & 7) << 4);
        bf16x8 vf = *(const bf16x8*)((const char*)lV[cur] + row * 128 + off);
        oacc[df] = __builtin_amdgcn_mfma_f32_16x16x32_bf16(pf, vf,
                                                           oacc[df], 0, 0, 0);
      }
    }
    __syncthreads();
  }

#pragma unroll
  for (int j = 0; j < 4; ++j) {
    int r = qrow0 + lg * 4 + j;
    float inv = 1.0f / lrun[j];
#pragma unroll
    for (int df = 0; df < 4; ++df)
      attnout[((size_t)(b * 1024 + r)) * 1024 + h * 64 + df * 16 + l15] =
          f2bf(oacc[df][j] * inv);
  }
}

extern "C" void kernel_launch(void* const* d_in, const int* in_sizes, int n_in,
                              void* d_out, int out_size, void* d_ws, size_t ws_size,
                              hipStream_t stream) {
  const float* queries = (const float*)d_in[0];
  const float* keys1 = (const float*)d_in[1];
  const float* keys2 = (const float*)d_in[2];
  const float* values = (const float*)d_in[3];
  const float* aw = (const float*)d_in[4];
  const void* mask = d_in[5];
  const float* Wq = (const float*)d_in[6];
  const float* bq = (const float*)d_in[7];
  const float* Wk1 = (const float*)d_in[8];
  const float* bk1 = (const float*)d_in[9];
  const float* Wk2 = (const float*)d_in[10];
  const float* bk2 = (const float*)d_in[11];
  const float* Wv = (const float*)d_in[12];
  const float* bv = (const float*)d_in[13];
  const float* Wo = (const float*)d_in[14];
  const float* bo = (const float*)d_in[15];

  char* ws = (char*)d_ws;
  unsigned short* qbf = (unsigned short*)(ws + (0ull << 20));
  unsigned short* khat = (unsigned short*)(ws + (8ull << 20));
  unsigned short* vTb = (unsigned short*)(ws + (16ull << 20));
  unsigned short* attno = (unsigned short*)(ws + (24ull << 20));
  unsigned short* WT = (unsigned short*)(ws + (32ull << 20));
  unsigned short* WoT = WT;
  unsigned short* WqT = WT + 1 * 1048576;
  unsigned short* Wk1T = WT + 2 * 1048576;
  unsigned short* Wk2T = WT + 3 * 1048576;
  unsigned short* WvT = WT + 4 * 1048576;

  transpose5_kernel<<<dim3(32, 32, 5), 256, 0, stream>>>(
      W5{Wo, Wq, Wk1, Wk2, Wv}, WT);

  P3 p{queries, keys1, keys2, values, WqT, Wk1T, Wk2T, WvT,
       bq, bk1, bk2, bv, qbf, khat, vTb};
  proj3_kernel<<<3072, 256, 0, stream>>>(p);

  attn_kernel<<<1024, 256, 0, stream>>>(qbf, khat, vTb, aw, mask, attno);

  const dim3 gg(64, 16);  // M/64, N/64
  gemm64_kernel<1><<<gg, 256, 0, stream>>>(attno, WoT, nullptr, nullptr,
                                           bo, nullptr, d_out, 4096, 1024, 1024, 2);
}